// Round 9
// baseline (401.496 us; speedup 1.0000x reference)
//
#include <hip/hip_runtime.h>
#include <hip/hip_bf16.h>
#include <hip/hip_fp16.h>

#define RMAXF 2.0f
#define PI_F 3.14159265358979f

// clang ext_vector types — __builtin_nontemporal_load requires these
typedef float f32x4 __attribute__((ext_vector_type(4)));
typedef int   i32x4 __attribute__((ext_vector_type(4)));

// LDS-resident Z coverage (bytes). 162304 + 120*8 + 16*4 = 163328 <= 163840.
#define LDS_COVER 162304

// ---------------------------------------------------------------------------
// Prologue: Z (int32, values < 119) -> uint8. The edge kernel stages 162K
// of this into LDS; tail atoms (>= cover, ~19%) gather from the compact
// 37 KB global remainder.
// ---------------------------------------------------------------------------
__global__ __launch_bounds__(256) void z_to_u8(
    const int* __restrict__ Z, unsigned char* __restrict__ zu8, int n)
{
    int i = blockIdx.x * blockDim.x + threadIdx.x;
    if (i < n) zu8[i] = (unsigned char)Z[i];
}

// ---------------------------------------------------------------------------
// Main kernel, r9: 16 edges per thread-iteration (was 8). Evidence (r8):
// latency-bound — 16 waves/CU x 10 outstanding loads = 2.8 B/cyc/CU streaming
// (1.35 TB/s measured). Doubling per-wave in-flight loads (8 idx + 12 dr +
// 32 lookups) targets ~2x the overlap. idx loads issued FIRST so the
// divergent lookups (which depend only on idx) wait on vmcnt(12), leaving
// the 12 dr loads still in flight while gathers issue.
// ---------------------------------------------------------------------------
__global__ __launch_bounds__(1024) void edge_kernel_lds(
    const f32x4* __restrict__ dr4,
    const i32x4* __restrict__ idx_i4,
    const i32x4* __restrict__ idx_j4,
    const unsigned char* __restrict__ zu8,
    const float* __restrict__ rep_scale,
    const float* __restrict__ rep_prefactor,
    float*       __restrict__ out,
    int n_hex, int n_edges, int cover)
{
    __shared__ unsigned char zs[LDS_COVER];
    __shared__ float2 tab[120];
    __shared__ float wsum[16];

    for (int t = threadIdx.x; t < 119; t += blockDim.x)
        tab[t] = make_float2(fabsf(rep_prefactor[t]),
                             1.0f / fabsf(rep_scale[t]));
    {   // stage zs cooperatively, 16B chunks (cover % 16 == 0)
        const i32x4* zsrc = (const i32x4*)zu8;
        i32x4* zdst = (i32x4*)zs;
        const int nvec = cover >> 4;
        for (int t = threadIdx.x; t < nvec; t += blockDim.x)
            zdst[t] = zsrc[t];
    }
    __syncthreads();

    float acc = 0.0f;
    const int stride = gridDim.x * blockDim.x;

    for (int h = blockIdx.x * blockDim.x + threadIdx.x; h < n_hex; h += stride) {
        // ---- issue idx loads first (gather dependencies) ----
        i32x4 iv[4], jv[4];
        #pragma unroll
        for (int t = 0; t < 4; ++t)
            iv[t] = __builtin_nontemporal_load(&idx_i4[4 * h + t]);
        #pragma unroll
        for (int t = 0; t < 4; ++t)
            jv[t] = __builtin_nontemporal_load(&idx_j4[4 * h + t]);
        // ---- then the 12 dr_vec loads (consumed last) ----
        f32x4 dv[12];
        #pragma unroll
        for (int t = 0; t < 12; ++t)
            dv[t] = __builtin_nontemporal_load(&dr4[12 * h + t]);

        int ii[16], jj[16];
        #pragma unroll
        for (int k = 0; k < 16; ++k) {
            ii[k] = iv[k >> 2][k & 3];
            jj[k] = jv[k >> 2][k & 3];
        }

        // ---- 32 lookups: LDS for a < cover (81%), global u8 tail else ----
        int zi[16], zj[16];
        #pragma unroll
        for (int k = 0; k < 16; ++k) {
            int a = ii[k], b = jj[k];
            zi[k] = (a < cover) ? (int)zs[a] : (int)zu8[a];
            zj[k] = (b < cover) ? (int)zs[b] : (int)zu8[b];
        }

        float d2[16];
        #pragma unroll
        for (int k = 0; k < 16; ++k) {
            float x = dv[(3 * k + 0) >> 2][(3 * k + 0) & 3];
            float y = dv[(3 * k + 1) >> 2][(3 * k + 1) & 3];
            float z = dv[(3 * k + 2) >> 2][(3 * k + 2) & 3];
            d2[k] = x * x + y * y + z * z;
        }

        #pragma unroll
        for (int k = 0; k < 16; ++k) {
            float2 pi_ = tab[zi[k]];
            float2 pj_ = tab[zj[k]];
            // clip(sqrt(d2), 0.02, 2) == sqrt(clip(d2, 4e-4, 4))
            float d2c = fminf(fmaxf(d2[k], 4.0e-4f), 4.0f);
            float dr  = __builtin_amdgcn_sqrtf(d2c);
            // 0.5*(cos(pi*dr/2)+1) == cos^2(pi*dr/4)
            float cv  = __cosf((0.25f * PI_F) * dr);
            float e   = __expf(-dr * (pi_.y + pj_.y));
            float f   = pi_.x * pj_.x * e * __builtin_amdgcn_rcpf(d2c) * cv * cv;
            acc += (ii[k] != jj[k]) ? f : 0.0f;
        }
    }

    // tail (n_edges % 16) — empty for 12.8M edges
    if (blockIdx.x == 0 && threadIdx.x == 0) {
        const float* drf = (const float*)dr4;
        const int* idx_i = (const int*)idx_i4;
        const int* idx_j = (const int*)idx_j4;
        for (int e = n_hex * 16; e < n_edges; ++e) {
            float x = drf[3 * e + 0], y = drf[3 * e + 1], z = drf[3 * e + 2];
            float d2c = fminf(fmaxf(x * x + y * y + z * z, 4.0e-4f), 4.0f);
            float dr  = sqrtf(d2c);
            float cv  = __cosf((0.25f * PI_F) * dr);
            int i = idx_i[e], j = idx_j[e];
            float2 pi_ = tab[zu8[i]];
            float2 pj_ = tab[zu8[j]];
            float f = pi_.x * pj_.x * __expf(-dr * (pi_.y + pj_.y)) / d2c * cv * cv;
            if (i != j) acc += f;
        }
    }

    // wave64 shuffle reduce -> 16-wave block reduce -> one atomic per block
    #pragma unroll
    for (int off = 32; off > 0; off >>= 1)
        acc += __shfl_down(acc, off, 64);

    int lane = threadIdx.x & 63;
    int wid  = threadIdx.x >> 6;
    if (lane == 0) wsum[wid] = acc;
    __syncthreads();
    if (threadIdx.x == 0) {
        float s = 0.0f;
        #pragma unroll
        for (int w = 0; w < 16; ++w) s += wsum[w];
        atomicAdd(out, s);
    }
}

// ---------------------------------------------------------------------------
// Fallback (ws too small or edge count not 4-aligned): Z int32 gather +
// LDS tab, grid-stride scalar. Correct but slower; not expected to be used.
// ---------------------------------------------------------------------------
__global__ __launch_bounds__(256) void edge_kernel_fallback(
    const float* __restrict__ drf,
    const int*   __restrict__ idx_i,
    const int*   __restrict__ idx_j,
    const int*   __restrict__ Z,
    const float* __restrict__ rep_scale,
    const float* __restrict__ rep_prefactor,
    float*       __restrict__ out,
    int n_edges)
{
    __shared__ float2 tab[128];
    for (int t = threadIdx.x; t < 119; t += blockDim.x)
        tab[t] = make_float2(fabsf(rep_prefactor[t]),
                             1.0f / fabsf(rep_scale[t]));
    __syncthreads();

    float acc = 0.0f;
    const int stride = gridDim.x * blockDim.x;
    for (int e = blockIdx.x * blockDim.x + threadIdx.x; e < n_edges; e += stride) {
        float x = drf[3 * e + 0], y = drf[3 * e + 1], z = drf[3 * e + 2];
        float d2c = fminf(fmaxf(x * x + y * y + z * z, 4.0e-4f), 4.0f);
        float dr  = __builtin_amdgcn_sqrtf(d2c);
        float cv  = __cosf((0.25f * PI_F) * dr);
        int i = idx_i[e], j = idx_j[e];
        float2 pi_ = tab[Z[i]], pj_ = tab[Z[j]];
        float f = pi_.x * pj_.x * __expf(-dr * (pi_.y + pj_.y))
                  * __builtin_amdgcn_rcpf(d2c) * cv * cv;
        acc += (i != j) ? f : 0.0f;
    }

    #pragma unroll
    for (int off = 32; off > 0; off >>= 1)
        acc += __shfl_down(acc, off, 64);
    __shared__ float wsum[4];
    int lane = threadIdx.x & 63;
    int wid  = threadIdx.x >> 6;
    if (lane == 0) wsum[wid] = acc;
    __syncthreads();
    if (threadIdx.x == 0)
        atomicAdd(out, wsum[0] + wsum[1] + wsum[2] + wsum[3]);
}

extern "C" void kernel_launch(void* const* d_in, const int* in_sizes, int n_in,
                              void* d_out, int out_size, void* d_ws, size_t ws_size,
                              hipStream_t stream) {
    // inputs: 0=R, 1=dr_vec, 2=Z, 3=idx, 4=box, 5=properties, 6=rep_scale, 7=rep_prefactor
    const float* dr_vec        = (const float*)d_in[1];
    const int*   Z             = (const int*)d_in[2];
    const int*   idx           = (const int*)d_in[3];
    const float* rep_scale     = (const float*)d_in[6];
    const float* rep_prefactor = (const float*)d_in[7];
    float* out = (float*)d_out;

    const int n_atoms = in_sizes[2];
    const int n_edges = in_sizes[3] / 2;       // idx is (2, N_EDGES)
    const int n_hex   = n_edges / 16;
    const int* idx_i = idx;
    const int* idx_j = idx + n_edges;

    // d_out poisoned 0xAA before every replay — zero on-stream
    (void)hipMemsetAsync(d_out, 0, sizeof(float), stream);

    // i32x4/f32x4 casts need idx_j (= idx + n_edges*4B) 16B-aligned
    const bool aligned = ((n_edges & 3) == 0);

    if (ws_size >= (size_t)n_atoms && aligned) {
        unsigned char* zu8 = (unsigned char*)d_ws;   // rebuilt every call
        z_to_u8<<<(n_atoms + 255) / 256, 256, 0, stream>>>(Z, zu8, n_atoms);

        int cover = n_atoms < LDS_COVER ? (n_atoms & ~15) : LDS_COVER;
        int blocks = (n_hex + 1023) / 1024;
        if (blocks > 256) blocks = 256;              // 1 block/CU (160KB LDS)
        edge_kernel_lds<<<blocks, 1024, 0, stream>>>(
            (const f32x4*)dr_vec, (const i32x4*)idx_i, (const i32x4*)idx_j,
            zu8, rep_scale, rep_prefactor, out, n_hex, n_edges, cover);
    } else {
        int blocks = (n_edges + 255) / 256;
        if (blocks > 4096) blocks = 4096;
        edge_kernel_fallback<<<blocks, 256, 0, stream>>>(
            dr_vec, idx_i, idx_j, Z, rep_scale, rep_prefactor, out, n_edges);
    }
}

// Round 11
// 390.780 us; speedup vs baseline: 1.0274x; 1.0274x over previous
//
#include <hip/hip_runtime.h>
#include <hip/hip_bf16.h>
#include <hip/hip_fp16.h>

#define RMAXF 2.0f
#define PI_F 3.14159265358979f

// clang ext_vector types — __builtin_nontemporal_load requires these
typedef float f32x4 __attribute__((ext_vector_type(4)));
typedef int   i32x4 __attribute__((ext_vector_type(4)));

// LDS-resident Z coverage (bytes). 162304 + 120*8 + 16*4 = 163328 <= 163840.
#define LDS_COVER 162304

// ---------------------------------------------------------------------------
// Prologue: Z (int32, values < 119) -> uint8. The edge kernel stages 162K
// of this into LDS; tail atoms (>= cover, ~19%) gather from the compact
// 37 KB global remainder.
// ---------------------------------------------------------------------------
__global__ __launch_bounds__(256) void z_to_u8(
    const int* __restrict__ Z, unsigned char* __restrict__ zu8, int n)
{
    int i = blockIdx.x * blockDim.x + threadIdx.x;
    if (i < n) zu8[i] = (unsigned char)Z[i];
}

// ---------------------------------------------------------------------------
// Main kernel, r10. Evidence chain:
//   r8 (8 edges/iter, 52 VGPR): 105us = Little's law, 2560 B in flight/CU
//     at ~900cy latency = 1.35 TB/s streaming. LDS-pinned at 16 waves/CU.
//   r9 (16 edges/iter, default bounds): compiler capped VGPR at 64 (assumed
//     8 waves/SIMD) -> 48 MB scratch spills -> 175us.
// Fix: __launch_bounds__(1024, 4) = our real occupancy (16 waves/CU =
// 4/SIMD) -> 128 VGPR cap. 16 edges/iter = 20 streaming loads (320 B) in
// flight per wave, 2x r8. Register economy: idx loads -> all 32 Z-lookups
// + masks (frees idx regs), then per-quad d2+math (frees dr regs).
// ---------------------------------------------------------------------------
__global__ __launch_bounds__(1024, 4) void edge_kernel_lds(
    const f32x4* __restrict__ dr4,
    const i32x4* __restrict__ idx_i4,
    const i32x4* __restrict__ idx_j4,
    const unsigned char* __restrict__ zu8,
    const float* __restrict__ rep_scale,
    const float* __restrict__ rep_prefactor,
    float*       __restrict__ out,
    int n_hex, int n_edges, int cover)
{
    __shared__ unsigned char zs[LDS_COVER];
    __shared__ float2 tab[120];
    __shared__ float wsum[16];

    for (int t = threadIdx.x; t < 119; t += blockDim.x)
        tab[t] = make_float2(fabsf(rep_prefactor[t]),
                             1.0f / fabsf(rep_scale[t]));
    {   // stage zs cooperatively, 16B chunks (cover % 16 == 0)
        const i32x4* zsrc = (const i32x4*)zu8;
        i32x4* zdst = (i32x4*)zs;
        const int nvec = cover >> 4;
        for (int t = threadIdx.x; t < nvec; t += blockDim.x)
            zdst[t] = zsrc[t];
    }
    __syncthreads();

    float acc = 0.0f;
    const int stride = gridDim.x * blockDim.x;

    for (int h = blockIdx.x * blockDim.x + threadIdx.x; h < n_hex; h += stride) {
        // ---- phase A: issue idx loads first, then dr (all 20 in flight) ----
        i32x4 iv[4], jv[4];
        #pragma unroll
        for (int t = 0; t < 4; ++t)
            iv[t] = __builtin_nontemporal_load(&idx_i4[4 * h + t]);
        #pragma unroll
        for (int t = 0; t < 4; ++t)
            jv[t] = __builtin_nontemporal_load(&idx_j4[4 * h + t]);
        f32x4 dv[12];
        #pragma unroll
        for (int t = 0; t < 12; ++t)
            dv[t] = __builtin_nontemporal_load(&dr4[12 * h + t]);

        // ---- phase B: all 32 Z-lookups + masks (waits idx only; dr still
        //      in flight thanks to FIFO vmcnt). Frees idx regs. ----
        int   zi[16], zj[16];
        float mk[16];
        #pragma unroll
        for (int k = 0; k < 16; ++k) {
            int a = iv[k >> 2][k & 3];
            int b = jv[k >> 2][k & 3];
            zi[k] = (a < cover) ? (int)zs[a] : (int)zu8[a];
            zj[k] = (b < cover) ? (int)zs[b] : (int)zu8[b];
            mk[k] = (a != b) ? 1.0f : 0.0f;
        }

        // ---- phase C: per-quad d2 + math (frees dv progressively) ----
        #pragma unroll
        for (int qd = 0; qd < 4; ++qd) {
            f32x4 a = dv[3 * qd + 0];
            f32x4 b = dv[3 * qd + 1];
            f32x4 c = dv[3 * qd + 2];
            float d2[4];
            d2[0] = a.x * a.x + a.y * a.y + a.z * a.z;
            d2[1] = a.w * a.w + b.x * b.x + b.y * b.y;
            d2[2] = b.z * b.z + b.w * b.w + c.x * c.x;
            d2[3] = c.y * c.y + c.z * c.z + c.w * c.w;
            #pragma unroll
            for (int t = 0; t < 4; ++t) {
                int k = 4 * qd + t;
                float2 pi_ = tab[zi[k]];
                float2 pj_ = tab[zj[k]];
                // clip(sqrt(d2), 0.02, 2) == sqrt(clip(d2, 4e-4, 4))
                float d2c = fminf(fmaxf(d2[t], 4.0e-4f), 4.0f);
                float dr  = __builtin_amdgcn_sqrtf(d2c);
                // 0.5*(cos(pi*dr/2)+1) == cos^2(pi*dr/4)
                float cv  = __cosf((0.25f * PI_F) * dr);
                float e   = __expf(-dr * (pi_.y + pj_.y));
                float f   = pi_.x * pj_.x * e * __builtin_amdgcn_rcpf(d2c) * cv * cv;
                acc += mk[k] * f;
            }
        }
    }

    // tail (n_edges % 16) — empty for 12.8M edges
    if (blockIdx.x == 0 && threadIdx.x == 0) {
        const float* drf = (const float*)dr4;
        const int* idx_i = (const int*)idx_i4;
        const int* idx_j = (const int*)idx_j4;
        for (int e = n_hex * 16; e < n_edges; ++e) {
            float x = drf[3 * e + 0], y = drf[3 * e + 1], z = drf[3 * e + 2];
            float d2c = fminf(fmaxf(x * x + y * y + z * z, 4.0e-4f), 4.0f);
            float dr  = sqrtf(d2c);
            float cv  = __cosf((0.25f * PI_F) * dr);
            int i = idx_i[e], j = idx_j[e];
            float2 pi_ = tab[zu8[i]];
            float2 pj_ = tab[zu8[j]];
            float f = pi_.x * pj_.x * __expf(-dr * (pi_.y + pj_.y)) / d2c * cv * cv;
            if (i != j) acc += f;
        }
    }

    // wave64 shuffle reduce -> 16-wave block reduce -> one atomic per block
    #pragma unroll
    for (int off = 32; off > 0; off >>= 1)
        acc += __shfl_down(acc, off, 64);

    int lane = threadIdx.x & 63;
    int wid  = threadIdx.x >> 6;
    if (lane == 0) wsum[wid] = acc;
    __syncthreads();
    if (threadIdx.x == 0) {
        float s = 0.0f;
        #pragma unroll
        for (int w = 0; w < 16; ++w) s += wsum[w];
        atomicAdd(out, s);
    }
}

// ---------------------------------------------------------------------------
// Fallback (ws too small or edge count not 4-aligned): Z int32 gather +
// LDS tab, grid-stride scalar. Correct but slower; not expected to be used.
// ---------------------------------------------------------------------------
__global__ __launch_bounds__(256) void edge_kernel_fallback(
    const float* __restrict__ drf,
    const int*   __restrict__ idx_i,
    const int*   __restrict__ idx_j,
    const int*   __restrict__ Z,
    const float* __restrict__ rep_scale,
    const float* __restrict__ rep_prefactor,
    float*       __restrict__ out,
    int n_edges)
{
    __shared__ float2 tab[128];
    for (int t = threadIdx.x; t < 119; t += blockDim.x)
        tab[t] = make_float2(fabsf(rep_prefactor[t]),
                             1.0f / fabsf(rep_scale[t]));
    __syncthreads();

    float acc = 0.0f;
    const int stride = gridDim.x * blockDim.x;
    for (int e = blockIdx.x * blockDim.x + threadIdx.x; e < n_edges; e += stride) {
        float x = drf[3 * e + 0], y = drf[3 * e + 1], z = drf[3 * e + 2];
        float d2c = fminf(fmaxf(x * x + y * y + z * z, 4.0e-4f), 4.0f);
        float dr  = __builtin_amdgcn_sqrtf(d2c);
        float cv  = __cosf((0.25f * PI_F) * dr);
        int i = idx_i[e], j = idx_j[e];
        float2 pi_ = tab[Z[i]], pj_ = tab[Z[j]];
        float f = pi_.x * pj_.x * __expf(-dr * (pi_.y + pj_.y))
                  * __builtin_amdgcn_rcpf(d2c) * cv * cv;
        acc += (i != j) ? f : 0.0f;
    }

    #pragma unroll
    for (int off = 32; off > 0; off >>= 1)
        acc += __shfl_down(acc, off, 64);
    __shared__ float wsum[4];
    int lane = threadIdx.x & 63;
    int wid  = threadIdx.x >> 6;
    if (lane == 0) wsum[wid] = acc;
    __syncthreads();
    if (threadIdx.x == 0)
        atomicAdd(out, wsum[0] + wsum[1] + wsum[2] + wsum[3]);
}

extern "C" void kernel_launch(void* const* d_in, const int* in_sizes, int n_in,
                              void* d_out, int out_size, void* d_ws, size_t ws_size,
                              hipStream_t stream) {
    // inputs: 0=R, 1=dr_vec, 2=Z, 3=idx, 4=box, 5=properties, 6=rep_scale, 7=rep_prefactor
    const float* dr_vec        = (const float*)d_in[1];
    const int*   Z             = (const int*)d_in[2];
    const int*   idx           = (const int*)d_in[3];
    const float* rep_scale     = (const float*)d_in[6];
    const float* rep_prefactor = (const float*)d_in[7];
    float* out = (float*)d_out;

    const int n_atoms = in_sizes[2];
    const int n_edges = in_sizes[3] / 2;       // idx is (2, N_EDGES)
    const int n_hex   = n_edges / 16;
    const int* idx_i = idx;
    const int* idx_j = idx + n_edges;

    // d_out poisoned 0xAA before every replay — zero on-stream
    (void)hipMemsetAsync(d_out, 0, sizeof(float), stream);

    // i32x4/f32x4 casts need idx_j (= idx + n_edges*4B) 16B-aligned
    const bool aligned = ((n_edges & 3) == 0);

    if (ws_size >= (size_t)n_atoms && aligned) {
        unsigned char* zu8 = (unsigned char*)d_ws;   // rebuilt every call
        z_to_u8<<<(n_atoms + 255) / 256, 256, 0, stream>>>(Z, zu8, n_atoms);

        int cover = n_atoms < LDS_COVER ? (n_atoms & ~15) : LDS_COVER;
        int blocks = (n_hex + 1023) / 1024;
        if (blocks > 256) blocks = 256;              // 1 block/CU (160KB LDS)
        edge_kernel_lds<<<blocks, 1024, 0, stream>>>(
            (const f32x4*)dr_vec, (const i32x4*)idx_i, (const i32x4*)idx_j,
            zu8, rep_scale, rep_prefactor, out, n_hex, n_edges, cover);
    } else {
        int blocks = (n_edges + 255) / 256;
        if (blocks > 4096) blocks = 4096;
        edge_kernel_fallback<<<blocks, 256, 0, stream>>>(
            dr_vec, idx_i, idx_j, Z, rep_scale, rep_prefactor, out, n_edges);
    }
}